// Round 14
// baseline (815.088 us; speedup 1.0000x reference)
//
#include <hip/hip_runtime.h>
#include <hip/hip_fp16.h>

// ---------------------------------------------------------------------------
// WQLinear_GEMM: out = x @ dequant(qweight,qzeros,scales) + bias
// detect -> fused prep (convert x || dequant Wt) -> 8-phase GEMM (m201 port).
// GEMM: 256x256 tile, BK=64, 8 waves (2M x 4N), LDS 128KB:
//   A [2buf][2kh][256][32], B same (+32768 shorts). chunk-XOR swizzle
//   (verified conflict-free r5). 4 phases per K-tile:
//   ph0: ds{bf ks0, af m0-3 ks0} | stage(T+1,kh1,A)->nxt | BAR lgkm0 16MFMA BAR
//   ph1: ds{af m4-7 ks0}         | stage(T+1,kh1,B)->nxt | VMC4 BAR lgkm0 16MFMA BAR
//   ph2: ds{bf ks1, af m0-3 ks1} | stage(T+2,kh0,A)->cur | BAR lgkm0 16MFMA BAR
//   ph3: ds{af m4-7 ks1}         | stage(T+2,kh0,B)->cur | VMC6 BAR lgkm0 16MFMA BAR
// Ledger (steady state, 2 loads/unit): entry outstanding 6 =
//   {(T,kh1,B),(T+1,kh0,A),(T+1,kh0,B)}. VMC4@ph1 drains those 3 units
//   (leaves (T+1,kh1,A/B)=4) -> ph2's kh1 reads and T+1's kh0 safe.
//   VMC6@ph3 drains (T+1,kh1,A), restoring the invariant. Never <4 in flight.
// WAR safety: (T+2,kh0,*) overwrites buf[cur].kh0 only in ph2/ph3 -- kh0
//   reads end at ph1's closing barrier. kh1 stages target buf[nxt] (not read).
// No sched_barrier on lgkm fences (r11: fences cost ~30us; C++ ds_reads have
//   compiler-visible deps so plain asm lgkmcnt(0) is safe).
// ---------------------------------------------------------------------------

#define K_DIM 4096
#define N_DIM 11008
#define M_DIM 8192
#define NPACK 1376   // N_DIM/8

typedef __attribute__((ext_vector_type(8))) short short8;
typedef __attribute__((ext_vector_type(4))) short short4v;
typedef __attribute__((ext_vector_type(4))) float f32x4;

__device__ __forceinline__ unsigned short f32_to_bf16(float f) {
    union { float f; unsigned int u; } v; v.f = f;
    unsigned int u = v.u;
    unsigned int r = (u + 0x7FFFu + ((u >> 16) & 1u)) >> 16;  // RNE
    return (unsigned short)r;
}
__device__ __forceinline__ float bf16_to_f32(unsigned short u) {
    union { float f; unsigned int i; } v; v.i = (unsigned int)u << 16;
    return v.f;
}
// t: 0 = f16, 1 = bf16, 2 = f32
__device__ __forceinline__ float load16(const void* p, long idx, int t) {
    if (t == 1) return bf16_to_f32(((const unsigned short*)p)[idx]);
    if (t == 2) return ((const float*)p)[idx];
    return __half2float(((const __half*)p)[idx]);
}

// ---------------- kernel 0: dtype detection ----------------
__global__ void detect_kernel(const void* __restrict__ sc,
                              const void* __restrict__ bi,
                              const void* __restrict__ x,
                              int* __restrict__ flags) {
    __shared__ int cnt[8];
    const int tid = threadIdx.x;
    if (tid < 8) cnt[tid] = 0;
    __syncthreads();
    int l[8] = {0,0,0,0,0,0,0,0};
#pragma unroll
    for (int j = 0; j < 8; ++j) {
        const int s = tid * 8 + j;            // 0..2047
        const int is = s * 86;
        { float v = __half2float(((const __half*)sc)[is]);      if (v > 1e-6f && v < 0.0101f) l[0]++; }
        { float v = bf16_to_f32(((const unsigned short*)sc)[is]); if (v > 1e-6f && v < 0.0101f) l[1]++; }
        { float v = ((const float*)sc)[is];                     if (v > 1e-6f && v < 0.0101f) l[2]++; }
        const int ib = s * 2 + 1;
        { float v = fabsf(__half2float(((const __half*)bi)[ib]));      if (v > 1e-5f && v < 0.08f) l[3]++; }
        { float v = fabsf(bf16_to_f32(((const unsigned short*)bi)[ib])); if (v > 1e-5f && v < 0.08f) l[4]++; }
        { float v = fabsf(((const float*)bi)[ib]);                     if (v > 1e-5f && v < 0.08f) l[5]++; }
        const long xi = (long)s * 8191 + 7;
        { float v = fabsf(((const float*)x)[xi]);                      if (v > 1e-5f && v < 20.f) l[6]++; }
        { float v = fabsf(bf16_to_f32(((const unsigned short*)x)[xi])); if (v > 1e-5f && v < 20.f) l[7]++; }
    }
#pragma unroll
    for (int i = 0; i < 8; ++i) atomicAdd(&cnt[i], l[i]);
    __syncthreads();
    if (tid == 0) {
        int st = 0; if (cnt[1] > cnt[st]) st = 1; if (cnt[2] > cnt[st]) st = 2;
        int bt = 0; if (cnt[4] > cnt[3 + bt]) bt = 1; if (cnt[5] > cnt[3 + bt]) bt = 2;
        const int xt = (cnt[7] >= (2048 * 9) / 10) ? 1 : 0;
        flags[0] = st; flags[1] = bt; flags[2] = xt;
    }
}

// ---------------- kernel 1: fused prep (convert x || dequant Wt) ----------------
#define CONV_BLOCKS 2048
#define DEQ_BLOCKS  5504
__global__ void prep_kernel(const void* __restrict__ xr,
                            unsigned short* __restrict__ xb,
                            const int* __restrict__ qw,
                            const int* __restrict__ qz,
                            const void* __restrict__ sc,
                            unsigned short* __restrict__ wt,
                            const int* __restrict__ flags) {
    if (blockIdx.x < CONV_BLOCKS) {
        const int xt = flags[2];
        int i = blockIdx.x * blockDim.x + threadIdx.x;
        const int stride = CONV_BLOCKS * 256;
        const int n8 = (M_DIM * K_DIM) / 8;
        if (xt == 0) {
            const float4* xf = (const float4*)xr;
            for (; i < n8; i += stride) {
                float4 a = xf[2 * i], b = xf[2 * i + 1];
                short8 v;
                v[0] = (short)f32_to_bf16(a.x); v[1] = (short)f32_to_bf16(a.y);
                v[2] = (short)f32_to_bf16(a.z); v[3] = (short)f32_to_bf16(a.w);
                v[4] = (short)f32_to_bf16(b.x); v[5] = (short)f32_to_bf16(b.y);
                v[6] = (short)f32_to_bf16(b.z); v[7] = (short)f32_to_bf16(b.w);
                reinterpret_cast<short8*>(xb)[i] = v;
            }
        } else {
            const short8* xs = (const short8*)xr;
            for (; i < n8; i += stride)
                reinterpret_cast<short8*>(xb)[i] = xs[i];
        }
    } else {
        const int st = flags[0];
        const int order[8] = {0, 4, 1, 5, 2, 6, 3, 7};
        int tid = (blockIdx.x - CONV_BLOCKS) * blockDim.x + threadIdx.x;
        const int stride = DEQ_BLOCKS * 256;
        for (; tid < K_DIM * NPACK; tid += stride) {
            const int k = tid & (K_DIM - 1);
            const int c = tid >> 12;
            const int g = k >> 7;
            const int w = qw[k * NPACK + c];
            const int z = qz[g * NPACK + c];
#pragma unroll
            for (int j = 0; j < 8; ++j) {
                const int sh = order[j] * 4;
                const int iw = (w >> sh) & 15;
                const int iz = (z >> sh) & 15;
                const float s = load16(sc, (long)g * N_DIM + c * 8 + j, st);
                wt[(size_t)(c * 8 + j) * K_DIM + k] = f32_to_bf16((float)(iw - iz) * s);
            }
        }
    }
}

// ---------------- kernel 2: 256x256 GEMM, 8-phase (m201 port) ----------------
#define G_BM 256
#define G_BN 256
#define G_BK 64
#define NT   (K_DIM / G_BK)   // 64

#define GLOAD(gptr, lptr) __builtin_amdgcn_global_load_lds( \
    (const __attribute__((address_space(1))) void*)(gptr),  \
    (__attribute__((address_space(3))) void*)(lptr), 16, 0, 0)

// A region: [2buf][2kh][256][32] shorts (64KB); B same at +32768 shorts.
#define LDS_AE(buf, kh, row, ch) \
    (lds + ((((buf) * 2 + (kh)) * 256 + (row)) * 32 + (ch) * 8))
#define LDS_BE(buf, kh, row, ch) \
    (lds + 32768 + ((((buf) * 2 + (kh)) * 256 + (row)) * 32 + (ch) * 8))

__global__ __launch_bounds__(512, 2) void gemm256_kernel(
    const unsigned short* __restrict__ A,   // xb [M][K]
    const unsigned short* __restrict__ B,   // Wt [N][K]
    const void* __restrict__ bias,
    const int* __restrict__ flags,
    float* __restrict__ C) {
    extern __shared__ unsigned short lds[];   // 128 KB

    const int bt = flags ? flags[1] : 0;

    const int tid  = threadIdx.x;
    const int lane = tid & 63;
    const int llo  = lane & 15;
    const int lhi  = lane >> 4;
    const int w    = tid >> 6;      // 0..7
    const int wr   = w >> 2;        // 0..1  (M half)
    const int wcn  = w & 3;         // 0..3  (N quarter)
    const int chsw = lhi ^ ((llo >> 1) & 3);   // conflict-free swizzled chunk

    // bijective XCD swizzle: 1376 = 8 * 172
    const int bid = blockIdx.x;
    const int swz = (bid & 7) * 172 + (bid >> 3);
    const int tm = swz / 43;
    const int tn = swz - tm * 43;
    const int row0 = tm * G_BM;
    const int col0 = tn * G_BN;

    // staging: thread -> (srow, schunk); source chunk pre-swizzled
    const int srow   = tid >> 2;                   // 0..127
    const int schunk = tid & 3;                    // 0..3
    const int cs     = schunk ^ ((srow >> 1) & 3);
    const unsigned short* Ab = A + (size_t)(row0 + srow) * K_DIM + cs * 8;
    const unsigned short* Bb = B + (size_t)(col0 + srow) * K_DIM + cs * 8;
    const size_t rstep = (size_t)128 * K_DIM;

#define STAGE_A(buf, kh, kofs) do {                                           \
    GLOAD(Ab + (kofs) + (kh) * 32,         LDS_AE(buf, kh, srow, schunk));    \
    GLOAD(Ab + (kofs) + (kh) * 32 + rstep, LDS_AE(buf, kh, srow + 128, schunk)); \
  } while (0)
#define STAGE_B(buf, kh, kofs) do {                                           \
    GLOAD(Bb + (kofs) + (kh) * 32,         LDS_BE(buf, kh, srow, schunk));    \
    GLOAD(Bb + (kofs) + (kh) * 32 + rstep, LDS_BE(buf, kh, srow + 128, schunk)); \
  } while (0)

#define VMC4  asm volatile("s_waitcnt vmcnt(4)" ::: "memory")
#define VMC6  asm volatile("s_waitcnt vmcnt(6)" ::: "memory")
#define LGKM0 asm volatile("s_waitcnt lgkmcnt(0)" ::: "memory")
#define BAR   __builtin_amdgcn_s_barrier()

#define RD_AF(kh, mofs)                                                       \
    _Pragma("unroll")                                                         \
    for (int m = 0; m < 4; ++m)                                               \
        af[m] = *reinterpret_cast<const short8*>(                             \
            LDS_AE(cur, kh, wr * 128 + ((mofs) + m) * 16 + llo, chsw));
#define RD_BF(kh)                                                             \
    _Pragma("unroll")                                                         \
    for (int n = 0; n < 4; ++n)                                               \
        bf[n] = *reinterpret_cast<const short8*>(                             \
            LDS_BE(cur, kh, wcn * 64 + n * 16 + llo, chsw));
#define MFMA16(mofs)                                                          \
    __builtin_amdgcn_s_setprio(1);                                            \
    _Pragma("unroll")                                                         \
    for (int m = 0; m < 4; ++m)                                               \
        _Pragma("unroll")                                                     \
        for (int n = 0; n < 4; ++n)                                           \
            acc[(mofs) + m][n] = __builtin_amdgcn_mfma_f32_16x16x32_bf16(     \
                af[m], bf[n], acc[(mofs) + m][n], 0, 0, 0);                   \
    __builtin_amdgcn_s_setprio(0);

    f32x4 acc[8][4] = {};
    short8 af[4], bf[4];

    // ---- prologue: tile0 (4 units) + (1,kh0) (2 units) = 12 loads ----
    STAGE_A(0, 0, 0);
    STAGE_B(0, 0, 0);
    STAGE_A(0, 1, 0);
    STAGE_B(0, 1, 0);
    STAGE_A(1, 0, G_BK);
    STAGE_B(1, 0, G_BK);
    VMC6;   // drains (0,kh0,A/B),(0,kh1,A); leaves (0,kh1,B),(1,kh0,A/B)
    BAR;

#pragma unroll 1
    for (int T = 0; T < NT; ++T) {
        const int cur = T & 1;
        const int nxt = cur ^ 1;
        const int k1 = (T + 1 < NT ? T + 1 : NT - 1) * G_BK;
        const int k2 = (T + 2 < NT ? T + 2 : NT - 1) * G_BK;

        // ---- ph0: ks0, m0-3 ----
        RD_BF(0)
        RD_AF(0, 0)
        STAGE_A(nxt, 1, k1);          // (T+1, kh1, A)
        BAR; LGKM0;
        MFMA16(0)
        BAR;

        // ---- ph1: ks0, m4-7 ----
        RD_AF(0, 4)
        STAGE_B(nxt, 1, k1);          // (T+1, kh1, B)
        VMC4;                         // lands (T,kh1,B),(T+1,kh0,A/B)
        BAR; LGKM0;
        MFMA16(4)
        BAR;

        // ---- ph2: ks1, m0-3 ----
        RD_BF(1)
        RD_AF(1, 0)
        STAGE_A(cur, 0, k2);          // (T+2, kh0, A) -- kh0 reads done ph1
        BAR; LGKM0;
        MFMA16(0)
        BAR;

        // ---- ph3: ks1, m4-7 ----
        RD_AF(1, 4)
        STAGE_B(cur, 0, k2);          // (T+2, kh0, B)
        VMC6;                         // lands (T+1,kh1,A); 6 stay in flight
        BAR; LGKM0;
        MFMA16(4)
        BAR;
    }

    // ---- epilogue: C = acc + bias (nontemporal stores) ----
#pragma unroll
    for (int n = 0; n < 4; ++n) {
        const int col = col0 + wcn * 64 + n * 16 + llo;
        const float bi = load16(bias, col, bt);
#pragma unroll
        for (int m = 0; m < 8; ++m) {
            const int row = row0 + wr * 128 + m * 16 + lhi * 4;
#pragma unroll
            for (int i = 0; i < 4; ++i)
                __builtin_nontemporal_store(acc[m][n][i] + bi,
                                            &C[(size_t)(row + i) * N_DIM + col]);
        }
    }
#undef STAGE_A
#undef STAGE_B
#undef VMC4
#undef VMC6
#undef LGKM0
#undef BAR
#undef RD_AF
#undef RD_BF
#undef MFMA16
}

// ---------------- fallback: fully-fused 128x128 (small ws) ----------------
#define BM 128
#define BN 128
#define BK 64
#define LDK 72

__global__ __launch_bounds__(256) void gemm_fused_kernel(
    const float* __restrict__ Af32,
    const int* __restrict__ qw,
    const int* __restrict__ qz,
    const void* __restrict__ sc,
    const void* __restrict__ bias,
    float* __restrict__ C) {
    __shared__ unsigned short As[BM][LDK];
    __shared__ unsigned short Bs[BN][LDK];
    const int tid  = threadIdx.x;
    const int lane = tid & 63;
    const int lhi  = lane >> 4;
    const int llo  = lane & 15;
    const int wv   = tid >> 6;
    const int wr   = wv >> 1;
    const int wc   = wv & 1;
    const int row0 = blockIdx.y * BM;
    const int col0 = blockIdx.x * BN;
    const int lrow = tid >> 3;
    const int lcol = (tid & 7) * 8;
    f32x4 acc[4][4] = {};
    for (int kt = 0; kt < K_DIM; kt += BK) {
#pragma unroll
        for (int r = 0; r < 4; ++r) {
            const float* p = Af32 + (size_t)(row0 + r * 32 + lrow) * K_DIM + kt + lcol;
            float4 x0 = *reinterpret_cast<const float4*>(p);
            float4 x1 = *reinterpret_cast<const float4*>(p + 4);
            short8 v;
            v[0] = (short)f32_to_bf16(x0.x); v[1] = (short)f32_to_bf16(x0.y);
            v[2] = (short)f32_to_bf16(x0.z); v[3] = (short)f32_to_bf16(x0.w);
            v[4] = (short)f32_to_bf16(x1.x); v[5] = (short)f32_to_bf16(x1.y);
            v[6] = (short)f32_to_bf16(x1.z); v[7] = (short)f32_to_bf16(x1.w);
            *reinterpret_cast<short8*>(&As[r * 32 + lrow][lcol]) = v;
        }
        {
            const int pc  = tid & 15;
            const int kq  = tid >> 4;
            const int g   = kt >> 7;
            const int pcg = (col0 >> 3) + pc;
            const int z   = qz[g * NPACK + pcg];
            int wv4[4];
#pragma unroll
            for (int q = 0; q < 4; ++q)
                wv4[q] = qw[(size_t)(kt + kq * 4 + q) * NPACK + pcg];
            const int order[8] = {0, 4, 1, 5, 2, 6, 3, 7};
#pragma unroll
            for (int j = 0; j < 8; ++j) {
                const int sh = order[j] * 4;
                const int zj = (z >> sh) & 15;
                const float sj = __half2float(((const __half*)sc)[(long)g * N_DIM + col0 + pc * 8 + j]);
                short4v o;
#pragma unroll
                for (int q = 0; q < 4; ++q) {
                    const int iw = (wv4[q] >> sh) & 15;
                    o[q] = (short)f32_to_bf16((float)(iw - zj) * sj);
                }
                *reinterpret_cast<short4v*>(&Bs[pc * 8 + j][kq * 4]) = o;
            }
        }
        __syncthreads();
#pragma unroll
        for (int kk = 0; kk < 2; ++kk) {
            const int ko = kk * 32 + lhi * 8;
            short8 af[4], bf[4];
#pragma unroll
            for (int m = 0; m < 4; ++m)
                af[m] = *reinterpret_cast<const short8*>(&As[wr * 64 + m * 16 + llo][ko]);
#pragma unroll
            for (int n = 0; n < 4; ++n)
                bf[n] = *reinterpret_cast<const short8*>(&Bs[wc * 64 + n * 16 + llo][ko]);
#pragma unroll
            for (int m = 0; m < 4; ++m)
#pragma unroll
                for (int n = 0; n < 4; ++n)
                    acc[m][n] = __builtin_amdgcn_mfma_f32_16x16x32_bf16(af[m], bf[n], acc[m][n], 0, 0, 0);
        }
        __syncthreads();
    }
#pragma unroll
    for (int n = 0; n < 4; ++n) {
        const int col = col0 + wc * 64 + n * 16 + llo;
        const float bi = __half2float(((const __half*)bias)[col]);
#pragma unroll
        for (int m = 0; m < 4; ++m) {
            const int row = row0 + wr * 64 + m * 16 + lhi * 4;
#pragma unroll
            for (int i = 0; i < 4; ++i)
                C[(size_t)(row + i) * N_DIM + col] = acc[m][n][i] + bi;
        }
    }
}

static const void* ptr_by_size(void* const* d_in, const int* in_sizes, int n_in,
                               long want, int def_idx) {
    for (int i = 0; i < n_in; ++i)
        if ((long)in_sizes[i] == want) return d_in[i];
    return d_in[def_idx];
}

extern "C" void kernel_launch(void* const* d_in, const int* in_sizes, int n_in,
                              void* d_out, int out_size, void* d_ws, size_t ws_size,
                              hipStream_t stream) {
    const void* x    = ptr_by_size(d_in, in_sizes, n_in, (long)M_DIM * K_DIM, 0);
    const int*  qw   = (const int*)ptr_by_size(d_in, in_sizes, n_in, (long)K_DIM * NPACK, 1);
    const int*  qz   = (const int*)ptr_by_size(d_in, in_sizes, n_in, (long)(K_DIM / 128) * NPACK, 2);
    const void* sc   = ptr_by_size(d_in, in_sizes, n_in, (long)(K_DIM / 128) * N_DIM, 3);
    const void* bias = ptr_by_size(d_in, in_sizes, n_in, (long)N_DIM, 4);
    float*      out  = (float*)d_out;

    const size_t xb_bytes = (size_t)M_DIM * K_DIM * 2;   // 67.1 MB
    const size_t wt_bytes = (size_t)N_DIM * K_DIM * 2;   // 90.2 MB
    unsigned short* xb = (unsigned short*)d_ws;
    unsigned short* wt = (unsigned short*)((char*)d_ws + xb_bytes);

    int* flags = nullptr;
    if (ws_size >= 32)
        flags = (int*)(((uintptr_t)d_ws + ws_size - 16) & ~(uintptr_t)15);

    if (flags && ws_size >= xb_bytes + wt_bytes + 32) {
        detect_kernel<<<1, 256, 0, stream>>>(sc, bias, x, flags);
        prep_kernel<<<CONV_BLOCKS + DEQ_BLOCKS, 256, 0, stream>>>(
            x, xb, qw, qz, sc, wt, flags);
        hipFuncSetAttribute(reinterpret_cast<const void*>(gemm256_kernel),
                            hipFuncAttributeMaxDynamicSharedMemorySize, 131072);
        gemm256_kernel<<<(M_DIM / G_BM) * (N_DIM / G_BN), 512, 131072, stream>>>(
            xb, wt, bias, flags, out);
    } else {
        dim3 grid(N_DIM / BN, M_DIM / BM);
        gemm_fused_kernel<<<grid, 256, 0, stream>>>(
            (const float*)x, qw, qz, sc, bias, out);
    }
}

// Round 15
// 810.947 us; speedup vs baseline: 1.0051x; 1.0051x over previous
//
#include <hip/hip_runtime.h>
#include <hip/hip_fp16.h>

// ---------------------------------------------------------------------------
// WQLinear_GEMM: out = x @ dequant(qweight,qzeros,scales) + bias
// detect -> fused prep (convert x || dequant Wt) -> GEMM.
// Round 15: r13 base (best, GEMM ~718us) with sync count HALVED:
//   BK 32 -> 64, 3-slot ring -> classic 2-slot double buffer (128KB LDS),
//   ONE s_barrier + ONE s_waitcnt vmcnt(0) per K-64 step (64 total vs 128).
// Rationale: r13 spends ~2250cyc/K32-step vs ~1170cyc LDS+MFMA floor; sync
// count is the only axis that tracked results across r5-r14 (r14 doubled
// syncs -> -10%). vmcnt(0) is ~free here: the 8 stage loads issue at step
// START and drain at step END (~4000cyc in flight >> 900cyc HBM latency).
// Register budget kept by processing kh-halves sequentially (12 live frags):
// ~90 VGPR + 128 acc-AGPR <= 256 -> 2 waves/SIMD preserved.
// Dbuf hazard proof: step T reads slot[cur] (landed: vmcnt(0)+BAR at end of
// T-1); STAGE at T writes slot[nxt] = slot read at T-1, whose reads all
// completed before the barrier ending T-1. One barrier/step suffices.
// ---------------------------------------------------------------------------

#define K_DIM 4096
#define N_DIM 11008
#define M_DIM 8192
#define NPACK 1376   // N_DIM/8

typedef __attribute__((ext_vector_type(8))) short short8;
typedef __attribute__((ext_vector_type(4))) short short4v;
typedef __attribute__((ext_vector_type(4))) float f32x4;

__device__ __forceinline__ unsigned short f32_to_bf16(float f) {
    union { float f; unsigned int u; } v; v.f = f;
    unsigned int u = v.u;
    unsigned int r = (u + 0x7FFFu + ((u >> 16) & 1u)) >> 16;  // RNE
    return (unsigned short)r;
}
__device__ __forceinline__ float bf16_to_f32(unsigned short u) {
    union { float f; unsigned int i; } v; v.i = (unsigned int)u << 16;
    return v.f;
}
// t: 0 = f16, 1 = bf16, 2 = f32
__device__ __forceinline__ float load16(const void* p, long idx, int t) {
    if (t == 1) return bf16_to_f32(((const unsigned short*)p)[idx]);
    if (t == 2) return ((const float*)p)[idx];
    return __half2float(((const __half*)p)[idx]);
}

// ---------------- kernel 0: dtype detection ----------------
__global__ void detect_kernel(const void* __restrict__ sc,
                              const void* __restrict__ bi,
                              const void* __restrict__ x,
                              int* __restrict__ flags) {
    __shared__ int cnt[8];
    const int tid = threadIdx.x;
    if (tid < 8) cnt[tid] = 0;
    __syncthreads();
    int l[8] = {0,0,0,0,0,0,0,0};
#pragma unroll
    for (int j = 0; j < 8; ++j) {
        const int s = tid * 8 + j;            // 0..2047
        const int is = s * 86;
        { float v = __half2float(((const __half*)sc)[is]);      if (v > 1e-6f && v < 0.0101f) l[0]++; }
        { float v = bf16_to_f32(((const unsigned short*)sc)[is]); if (v > 1e-6f && v < 0.0101f) l[1]++; }
        { float v = ((const float*)sc)[is];                     if (v > 1e-6f && v < 0.0101f) l[2]++; }
        const int ib = s * 2 + 1;
        { float v = fabsf(__half2float(((const __half*)bi)[ib]));      if (v > 1e-5f && v < 0.08f) l[3]++; }
        { float v = fabsf(bf16_to_f32(((const unsigned short*)bi)[ib])); if (v > 1e-5f && v < 0.08f) l[4]++; }
        { float v = fabsf(((const float*)bi)[ib]);                     if (v > 1e-5f && v < 0.08f) l[5]++; }
        const long xi = (long)s * 8191 + 7;
        { float v = fabsf(((const float*)x)[xi]);                      if (v > 1e-5f && v < 20.f) l[6]++; }
        { float v = fabsf(bf16_to_f32(((const unsigned short*)x)[xi])); if (v > 1e-5f && v < 20.f) l[7]++; }
    }
#pragma unroll
    for (int i = 0; i < 8; ++i) atomicAdd(&cnt[i], l[i]);
    __syncthreads();
    if (tid == 0) {
        int st = 0; if (cnt[1] > cnt[st]) st = 1; if (cnt[2] > cnt[st]) st = 2;
        int bt = 0; if (cnt[4] > cnt[3 + bt]) bt = 1; if (cnt[5] > cnt[3 + bt]) bt = 2;
        const int xt = (cnt[7] >= (2048 * 9) / 10) ? 1 : 0;
        flags[0] = st; flags[1] = bt; flags[2] = xt;
    }
}

// ---------------- kernel 1: fused prep (convert x || dequant Wt) ----------------
#define CONV_BLOCKS 2048
#define DEQ_BLOCKS  5504
__global__ void prep_kernel(const void* __restrict__ xr,
                            unsigned short* __restrict__ xb,
                            const int* __restrict__ qw,
                            const int* __restrict__ qz,
                            const void* __restrict__ sc,
                            unsigned short* __restrict__ wt,
                            const int* __restrict__ flags) {
    if (blockIdx.x < CONV_BLOCKS) {
        const int xt = flags[2];
        int i = blockIdx.x * blockDim.x + threadIdx.x;
        const int stride = CONV_BLOCKS * 256;
        const int n8 = (M_DIM * K_DIM) / 8;
        if (xt == 0) {
            const float4* xf = (const float4*)xr;
            for (; i < n8; i += stride) {
                float4 a = xf[2 * i], b = xf[2 * i + 1];
                short8 v;
                v[0] = (short)f32_to_bf16(a.x); v[1] = (short)f32_to_bf16(a.y);
                v[2] = (short)f32_to_bf16(a.z); v[3] = (short)f32_to_bf16(a.w);
                v[4] = (short)f32_to_bf16(b.x); v[5] = (short)f32_to_bf16(b.y);
                v[6] = (short)f32_to_bf16(b.z); v[7] = (short)f32_to_bf16(b.w);
                reinterpret_cast<short8*>(xb)[i] = v;
            }
        } else {
            const short8* xs = (const short8*)xr;
            for (; i < n8; i += stride)
                reinterpret_cast<short8*>(xb)[i] = xs[i];
        }
    } else {
        const int st = flags[0];
        const int order[8] = {0, 4, 1, 5, 2, 6, 3, 7};
        int tid = (blockIdx.x - CONV_BLOCKS) * blockDim.x + threadIdx.x;
        const int stride = DEQ_BLOCKS * 256;
        for (; tid < K_DIM * NPACK; tid += stride) {
            const int k = tid & (K_DIM - 1);
            const int c = tid >> 12;
            const int g = k >> 7;
            const int w = qw[k * NPACK + c];
            const int z = qz[g * NPACK + c];
#pragma unroll
            for (int j = 0; j < 8; ++j) {
                const int sh = order[j] * 4;
                const int iw = (w >> sh) & 15;
                const int iz = (z >> sh) & 15;
                const float s = load16(sc, (long)g * N_DIM + c * 8 + j, st);
                wt[(size_t)(c * 8 + j) * K_DIM + k] = f32_to_bf16((float)(iw - iz) * s);
            }
        }
    }
}

// ---------------- kernel 2: 256x256 GEMM, BK=64, 2-slot dbuf ----------------
#define G_BM 256
#define G_BN 256
#define G_BK 64
#define NSTEP (K_DIM / G_BK)   // 64
#define SLOT  32768            // shorts/slot: A [2kh][256][32]=16K + B 16K

#define GLOAD(gptr, lptr) __builtin_amdgcn_global_load_lds( \
    (const __attribute__((address_space(1))) void*)(gptr),  \
    (__attribute__((address_space(3))) void*)(lptr), 16, 0, 0)

__global__ __launch_bounds__(512, 2) void gemm256_kernel(
    const unsigned short* __restrict__ A,   // xb [M][K]
    const unsigned short* __restrict__ B,   // Wt [N][K]
    const void* __restrict__ bias,
    const int* __restrict__ flags,
    float* __restrict__ C) {
    extern __shared__ unsigned short lds[];   // 2 slots x 64KB = 128KB

    const int bt = flags ? flags[1] : 0;

    const int tid  = threadIdx.x;
    const int lane = tid & 63;
    const int llo  = lane & 15;
    const int lhi  = lane >> 4;
    const int w    = tid >> 6;      // 0..7
    const int wr   = w >> 2;        // 0..1  (M half)
    const int wcn  = w & 3;         // 0..3  (N quarter)
    const int chsw = lhi ^ ((llo >> 1) & 3);   // conflict-free swizzled chunk

    // bijective XCD swizzle: 1376 = 8 * 172
    const int bid = blockIdx.x;
    const int swz = (bid & 7) * 172 + (bid >> 3);
    const int tm = swz / 43;
    const int tn = swz - tm * 43;
    const int row0 = tm * G_BM;
    const int col0 = tn * G_BN;

    // staging: thread -> (srow, schunk); source chunk pre-swizzled
    const int srow   = tid >> 2;                   // 0..127
    const int schunk = tid & 3;                    // 0..3
    const int cs     = schunk ^ ((srow >> 1) & 3);
    const unsigned short* Ab = A + (size_t)(row0 + srow) * K_DIM + cs * 8;
    const unsigned short* Bb = B + (size_t)(col0 + srow) * K_DIM + cs * 8;
    const size_t rstep = (size_t)128 * K_DIM;
    const int dofs = srow * 32 + schunk * 8;       // within a [256][32] kh panel

    // slot layout (shorts): A kh0 @0, A kh1 @8192, B kh0 @16384, B kh1 @24576
#define STAGE(slot, kofs) do {                                                \
    GLOAD(Ab + (kofs),              lds + (slot) + dofs);                     \
    GLOAD(Ab + (kofs) + rstep,      lds + (slot) + 4096 + dofs);              \
    GLOAD(Ab + (kofs) + 32,         lds + (slot) + 8192 + dofs);              \
    GLOAD(Ab + (kofs) + 32 + rstep, lds + (slot) + 12288 + dofs);             \
    GLOAD(Bb + (kofs),              lds + (slot) + 16384 + dofs);             \
    GLOAD(Bb + (kofs) + rstep,      lds + (slot) + 20480 + dofs);             \
    GLOAD(Bb + (kofs) + 32,         lds + (slot) + 24576 + dofs);             \
    GLOAD(Bb + (kofs) + 32 + rstep, lds + (slot) + 28672 + dofs);             \
  } while (0)

#define VMC0 asm volatile("s_waitcnt vmcnt(0)" ::: "memory")
#define BAR  __builtin_amdgcn_s_barrier()

    f32x4 acc[8][4] = {};
    short8 af[8], bf[4];

    // prologue: stage tile 0
    STAGE(0, 0);
    VMC0;
    BAR;

    int s_cur = 0, s_nxt = SLOT;

#pragma unroll 1
    for (int T = 0; T < NSTEP; ++T) {
        const int kofs = (T + 1 < NSTEP ? T + 1 : NSTEP - 1) * G_BK;

        // ---- issue next-tile stage FIRST (8 gloads ride VMEM all step) ----
        STAGE(s_nxt, kofs);

        // ---- kh0: front-load 12 reads, 32 MFMA ----
#pragma unroll
        for (int n = 0; n < 4; ++n) {
            const int r = wcn * 64 + n * 16 + llo;
            bf[n] = *reinterpret_cast<const short8*>(lds + s_cur + 16384 + r * 32 + chsw * 8);
        }
#pragma unroll
        for (int m = 0; m < 8; ++m) {
            const int r = wr * 128 + m * 16 + llo;
            af[m] = *reinterpret_cast<const short8*>(lds + s_cur + r * 32 + chsw * 8);
        }
        __builtin_amdgcn_s_setprio(1);
#pragma unroll
        for (int m = 0; m < 8; ++m)
#pragma unroll
            for (int n = 0; n < 4; ++n)
                acc[m][n] = __builtin_amdgcn_mfma_f32_16x16x32_bf16(af[m], bf[n], acc[m][n], 0, 0, 0);
        __builtin_amdgcn_s_setprio(0);

        // ---- kh1: front-load 12 reads, 32 MFMA (no barrier needed) ----
#pragma unroll
        for (int n = 0; n < 4; ++n) {
            const int r = wcn * 64 + n * 16 + llo;
            bf[n] = *reinterpret_cast<const short8*>(lds + s_cur + 24576 + r * 32 + chsw * 8);
        }
#pragma unroll
        for (int m = 0; m < 8; ++m) {
            const int r = wr * 128 + m * 16 + llo;
            af[m] = *reinterpret_cast<const short8*>(lds + s_cur + 8192 + r * 32 + chsw * 8);
        }
        __builtin_amdgcn_s_setprio(1);
#pragma unroll
        for (int m = 0; m < 8; ++m)
#pragma unroll
            for (int n = 0; n < 4; ++n)
                acc[m][n] = __builtin_amdgcn_mfma_f32_16x16x32_bf16(af[m], bf[n], acc[m][n], 0, 0, 0);
        __builtin_amdgcn_s_setprio(0);

        VMC0;    // next tile fully landed (loads were in flight ~all step)
        BAR;     // all waves done reading slot[T]; swap safe
        const int t = s_cur; s_cur = s_nxt; s_nxt = t;
    }

    // ---- epilogue: C = acc + bias (nontemporal stores) ----
#pragma unroll
    for (int n = 0; n < 4; ++n) {
        const int col = col0 + wcn * 64 + n * 16 + llo;
        const float bi = load16(bias, col, bt);
#pragma unroll
        for (int m = 0; m < 8; ++m) {
            const int row = row0 + wr * 128 + m * 16 + lhi * 4;
#pragma unroll
            for (int i = 0; i < 4; ++i)
                __builtin_nontemporal_store(acc[m][n][i] + bi,
                                            &C[(size_t)(row + i) * N_DIM + col]);
        }
    }
#undef STAGE
#undef VMC0
#undef BAR
}

// ---------------- fallback: fully-fused 128x128 (small ws) ----------------
#define BM 128
#define BN 128
#define BK 64
#define LDK 72

__global__ __launch_bounds__(256) void gemm_fused_kernel(
    const float* __restrict__ Af32,
    const int* __restrict__ qw,
    const int* __restrict__ qz,
    const void* __restrict__ sc,
    const void* __restrict__ bias,
    float* __restrict__ C) {
    __shared__ unsigned short As[BM][LDK];
    __shared__ unsigned short Bs[BN][LDK];
    const int tid  = threadIdx.x;
    const int lane = tid & 63;
    const int lhi  = lane >> 4;
    const int llo  = lane & 15;
    const int wv   = tid >> 6;
    const int wr   = wv >> 1;
    const int wc   = wv & 1;
    const int row0 = blockIdx.y * BM;
    const int col0 = blockIdx.x * BN;
    const int lrow = tid >> 3;
    const int lcol = (tid & 7) * 8;
    f32x4 acc[4][4] = {};
    for (int kt = 0; kt < K_DIM; kt += BK) {
#pragma unroll
        for (int r = 0; r < 4; ++r) {
            const float* p = Af32 + (size_t)(row0 + r * 32 + lrow) * K_DIM + kt + lcol;
            float4 x0 = *reinterpret_cast<const float4*>(p);
            float4 x1 = *reinterpret_cast<const float4*>(p + 4);
            short8 v;
            v[0] = (short)f32_to_bf16(x0.x); v[1] = (short)f32_to_bf16(x0.y);
            v[2] = (short)f32_to_bf16(x0.z); v[3] = (short)f32_to_bf16(x0.w);
            v[4] = (short)f32_to_bf16(x1.x); v[5] = (short)f32_to_bf16(x1.y);
            v[6] = (short)f32_to_bf16(x1.z); v[7] = (short)f32_to_bf16(x1.w);
            *reinterpret_cast<short8*>(&As[r * 32 + lrow][lcol]) = v;
        }
        {
            const int pc  = tid & 15;
            const int kq  = tid >> 4;
            const int g   = kt >> 7;
            const int pcg = (col0 >> 3) + pc;
            const int z   = qz[g * NPACK + pcg];
            int wv4[4];
#pragma unroll
            for (int q = 0; q < 4; ++q)
                wv4[q] = qw[(size_t)(kt + kq * 4 + q) * NPACK + pcg];
            const int order[8] = {0, 4, 1, 5, 2, 6, 3, 7};
#pragma unroll
            for (int j = 0; j < 8; ++j) {
                const int sh = order[j] * 4;
                const int zj = (z >> sh) & 15;
                const float sj = __half2float(((const __half*)sc)[(long)g * N_DIM + col0 + pc * 8 + j]);
                short4v o;
#pragma unroll
                for (int q = 0; q < 4; ++q) {
                    const int iw = (wv4[q] >> sh) & 15;
                    o[q] = (short)f32_to_bf16((float)(iw - zj) * sj);
                }
                *reinterpret_cast<short4v*>(&Bs[pc * 8 + j][kq * 4]) = o;
            }
        }
        __syncthreads();
#pragma unroll
        for (int kk = 0; kk < 2; ++kk) {
            const int ko = kk * 32 + lhi * 8;
            short8 af[4], bf[4];
#pragma unroll
            for (int m = 0; m < 4; ++m)
                af[m] = *reinterpret_cast<const short8*>(&As[wr * 64 + m * 16 + llo][ko]);
#pragma unroll
            for (int n = 0; n < 4; ++n)
                bf[n] = *reinterpret_cast<const short8*>(&Bs[wc * 64 + n * 16 + llo][ko]);
#pragma unroll
            for (int m = 0; m < 4; ++m)
#pragma unroll
                for (int n = 0; n < 4; ++n)
                    acc[m][n] = __builtin_amdgcn_mfma_f32_16x16x32_bf16(af[m], bf[n], acc[m][n], 0, 0, 0);
        }
        __syncthreads();
    }
#pragma unroll
    for (int n = 0; n < 4; ++n) {
        const int col = col0 + wc * 64 + n * 16 + llo;
        const float bi = __half2float(((const __half*)bias)[col]);
#pragma unroll
        for (int m = 0; m < 4; ++m) {
            const int row = row0 + wr * 64 + m * 16 + lhi * 4;
#pragma unroll
            for (int i = 0; i < 4; ++i)
                C[(size_t)(row + i) * N_DIM + col] = acc[m][n][i] + bi;
        }
    }
}

static const void* ptr_by_size(void* const* d_in, const int* in_sizes, int n_in,
                               long want, int def_idx) {
    for (int i = 0; i < n_in; ++i)
        if ((long)in_sizes[i] == want) return d_in[i];
    return d_in[def_idx];
}

extern "C" void kernel_launch(void* const* d_in, const int* in_sizes, int n_in,
                              void* d_out, int out_size, void* d_ws, size_t ws_size,
                              hipStream_t stream) {
    const void* x    = ptr_by_size(d_in, in_sizes, n_in, (long)M_DIM * K_DIM, 0);
    const int*  qw   = (const int*)ptr_by_size(d_in, in_sizes, n_in, (long)K_DIM * NPACK, 1);
    const int*  qz   = (const int*)ptr_by_size(d_in, in_sizes, n_in, (long)(K_DIM / 128) * NPACK, 2);
    const void* sc   = ptr_by_size(d_in, in_sizes, n_in, (long)(K_DIM / 128) * N_DIM, 3);
    const void* bias = ptr_by_size(d_in, in_sizes, n_in, (long)N_DIM, 4);
    float*      out  = (float*)d_out;

    const size_t xb_bytes = (size_t)M_DIM * K_DIM * 2;   // 67.1 MB
    const size_t wt_bytes = (size_t)N_DIM * K_DIM * 2;   // 90.2 MB
    unsigned short* xb = (unsigned short*)d_ws;
    unsigned short* wt = (unsigned short*)((char*)d_ws + xb_bytes);

    int* flags = nullptr;
    if (ws_size >= 32)
        flags = (int*)(((uintptr_t)d_ws + ws_size - 16) & ~(uintptr_t)15);

    if (flags && ws_size >= xb_bytes + wt_bytes + 32) {
        detect_kernel<<<1, 256, 0, stream>>>(sc, bias, x, flags);
        prep_kernel<<<CONV_BLOCKS + DEQ_BLOCKS, 256, 0, stream>>>(
            x, xb, qw, qz, sc, wt, flags);
        hipFuncSetAttribute(reinterpret_cast<const void*>(gemm256_kernel),
                            hipFuncAttributeMaxDynamicSharedMemorySize, 131072);
        gemm256_kernel<<<(M_DIM / G_BM) * (N_DIM / G_BN), 512, 131072, stream>>>(
            xb, wt, bias, flags, out);
    } else {
        dim3 grid(N_DIM / BN, M_DIM / BM);
        gemm_fused_kernel<<<grid, 256, 0, stream>>>(
            (const float*)x, qw, qz, sc, bias, out);
    }
}